// Round 7
// baseline (35.692 us; speedup 1.0000x reference)
//
#include <hip/hip_runtime.h>

typedef float v2 __attribute__((ext_vector_type(2)));

__device__ __forceinline__ float frcp(float x){ return __builtin_amdgcn_rcpf(x); }
__device__ __forceinline__ v2 rcp2(v2 a){ v2 r; r.x = frcp(a.x); r.y = frcp(a.y); return r; }
__device__ __forceinline__ v2 min2(v2 a, v2 b){ v2 r; r.x = fminf(a.x,b.x); r.y = fminf(a.y,b.y); return r; }
__device__ __forceinline__ v2 max2(v2 a, v2 b){ v2 r; r.x = fmaxf(a.x,b.x); r.y = fmaxf(a.y,b.y); return r; }

// Liang-Barsky clip of segment p0 + t*d, t in [0,1], vs box [lo,hi].
// id = 1/d (precomputed). Returns cross(P(t0),P(t1)) of kept piece, 0 if empty.
__device__ __forceinline__ float lb_edge(v2 p0, v2 d, v2 id, v2 lo, v2 hi)
{
    v2 ta = (lo - p0) * id;
    v2 tb = (hi - p0) * id;
    v2 tmn = min2(ta, tb);
    v2 tmx = max2(ta, tb);
    float t0 = fmaxf(fmaxf(tmn.x, tmn.y), 0.f);   // v_max3
    float t1 = fminf(fminf(tmx.x, tmx.y), 1.f);   // v_min3
    v2 pa = (v2){t0, t0} * d + p0;                // v_pk_fma (op_sel splat)
    v2 pb = (v2){t1, t1} * d + p0;
    float c = fmaf(pa.x, pb.y, -(pa.y * pb.x));
    return (t1 > t0) ? c : 0.f;
}

// Quad centered cb with half-edge vectors u,v (corners cb +- u +- v in ref CCW
// order), clipped vs axis-aligned box [lo,hi]. Green sum of kept sub-segments.
// Edge deltas are -2u, -2v, +2u, +2v -> 2 rcp2 total.
__device__ __forceinline__ float clip_quad(v2 cb, v2 u, v2 v, v2 lo, v2 hi)
{
    v2 up = u + v, um = u - v;
    v2 g0 = cb + up, g1 = cb - um, g2 = cb - up, g3 = cb + um;
    v2 du2 = u + u, dv2 = v + v;
    v2 idu = rcp2(du2), idv = rcp2(dv2);
    float s = lb_edge(g0, -du2, -idu, lo, hi);
    s += lb_edge(g1, -dv2, -idv, lo, hi);
    s += lb_edge(g2,  du2,  idu, lo, hi);
    s += lb_edge(g3,  dv2,  idv, lo, hi);
    return s;
}

__global__ __launch_bounds__(256) void giou_kernel(
    const float* __restrict__ pred, const float* __restrict__ target,
    unsigned long long* __restrict__ counter, float* __restrict__ out,
    int n, int nb, double dscale)
{
    int i = blockIdx.x * blockDim.x + threadIdx.x;
    float loss = 0.0f;
    if (i < n) {
        const float p0 = pred[5*i+0], p1 = pred[5*i+1], p2 = pred[5*i+2], p3 = pred[5*i+3], p4 = pred[5*i+4];
        const float q0 = target[5*i+0], q1 = target[5*i+1], q2 = target[5*i+2], q3 = target[5*i+3], q4 = target[5*i+4];

        const float hw1 = 0.5f*p2, hh1 = 0.5f*p3, hw2 = 0.5f*q2, hh2 = 0.5f*q3;
        const v2 oa = { 0.5f*(p0 - q0), 0.5f*(p1 - q1) };   // A center rel. midpoint (B = -oa)

        const float cs1 = __cosf(p4), sn1 = __sinf(p4);
        const float cs2 = __cosf(q4), sn2 = __sinf(q4);
        const float cD = cs1*cs2 + sn1*sn2;   // cos(a2-a1)
        const float sD = sn2*cs1 - cs2*sn1;   // sin(a2-a1)

        // ---- frame A (world rotated by -a1): A center caA, B center -caA ----
        const v2 caA = oa.x * (v2){cs1, -sn1} + oa.y * (v2){sn1, cs1};
        const v2 hA  = {hw1, hh1};
        float twoA = clip_quad(-caA,
                               hw2 * (v2){cD, sD}, hh2 * (v2){-sD, cD},
                               caA - hA, caA + hA);

        // ---- frame B (world rotated by -a2): A center caB, box B at -caB ----
        const v2 caB = oa.x * (v2){cs2, -sn2} + oa.y * (v2){sn2, cs2};
        const v2 hB  = {hw2, hh2};
        twoA += clip_quad(caB,
                          hw1 * (v2){cD, -sD}, hh1 * (v2){sD, cD},
                          -caB - hB, -caB + hB);

        float inter_area = 0.5f * fabsf(twoA);

        // ---- union / iou ----
        float unionv = p2*p3 + q2*q3 - inter_area;
        float iou = fmaxf(inter_area * frcp(unionv), 1e-6f);

        // ---- smallest enclosing rect: 2 distinct dirs, closed form ----
        float acd = fabsf(cD), asd = fabsf(sD);
        float eBx = hw2*acd + hh2*asd, eBy = hw2*asd + hh2*acd;
        float w1 = fmaxf(caA.x + hw1, -caA.x + eBx) - fminf(caA.x - hw1, -caA.x - eBx);
        float h1 = fmaxf(caA.y + hh1, -caA.y + eBy) - fminf(caA.y - hh1, -caA.y - eBy);
        float a1 = w1*h1;
        float eAx = hw1*acd + hh1*asd, eAy = hw1*asd + hh1*acd;
        float w2 = fmaxf(caB.x + eAx, -caB.x + hw2) - fminf(caB.x - eAx, -caB.x - hw2);
        float h2 = fmaxf(caB.y + eAy, -caB.y + hh2) - fminf(caB.y - eAy, -caB.y - hh2);
        float a2 = w2*h2;

        float area_c = (a2 < a1) ? a2 : a1;   // box1 dirs first in ref argmin

        float r = (area_c - unionv) * frcp(area_c);
        float giou = iou*iou*iou - r*r*r;
        loss = 1.0f - giou;                   // loss >= 0 (r >= 0, iou <= 1)
    }

    // ---- deterministic block reduction ----
    #pragma unroll
    for (int off = 32; off; off >>= 1) loss += __shfl_down(loss, off, 64);
    __shared__ float smem[4];
    int lane = threadIdx.x & 63, wid = threadIdx.x >> 6;
    if (lane == 0) smem[wid] = loss;
    __syncthreads();

    // ---- single-pass finish: exact integer atomic, last block writes out ----
    // packed = arrival_tick<<48 | fixed_point_sum (scale 2^24). Integer adds
    // commute exactly -> bit-deterministic; no fences needed (the value rides
    // the atomic). Sum bound: 500k * 2 * 2^24 = 2^44 < 2^48.
    if (threadIdx.x == 0) {
        float bsum = smem[0] + smem[1] + smem[2] + smem[3];
        unsigned long long fixed = (unsigned long long)llrint((double)bsum * 16777216.0);
        unsigned long long packed = (1ULL << 48) | fixed;
        unsigned long long old = atomicAdd(counter, packed);
        if ((old >> 48) == (unsigned long long)(nb - 1)) {
            unsigned long long total = (old + packed) & ((1ULL << 48) - 1ULL);
            out[0] = (float)((double)total * dscale);
        }
    }
}

extern "C" void kernel_launch(void* const* d_in, const int* in_sizes, int n_in,
                              void* d_out, int out_size, void* d_ws, size_t ws_size,
                              hipStream_t stream) {
    const float* pred   = (const float*)d_in[0];
    const float* target = (const float*)d_in[1];
    float* out = (float*)d_out;
    unsigned long long* counter = (unsigned long long*)d_ws;
    int n  = in_sizes[0] / 5;
    int nb = (n + 255) / 256;
    double dscale = 1.0 / (16777216.0 * (double)n);   // 2^-24 / n
    hipMemsetAsync(counter, 0, 8, stream);            // reset ticket+sum (memset node)
    giou_kernel<<<nb, 256, 0, stream>>>(pred, target, counter, out, n, nb, dscale);
}

// Round 8
// 16.046 us; speedup vs baseline: 2.2244x; 2.2244x over previous
//
#include <hip/hip_runtime.h>

__device__ __forceinline__ float frcp(float x){ return __builtin_amdgcn_rcpf(x); }

// Liang-Barsky clip of segment E0->E1 against axis-aligned box [lx,hx]x[ly,hy].
// Returns cross(P(t0), P(t1)) of the kept sub-segment, 0 if empty.
__device__ __forceinline__ float lb_edge(float x0, float y0, float x1, float y1,
                                         float lx, float hx, float ly, float hy)
{
    float dx = x1 - x0, dy = y1 - y0;
    float idx = frcp(dx), idy = frcp(dy);
    float ta = (lx - x0) * idx, tb = (hx - x0) * idx;
    float tc = (ly - y0) * idy, td = (hy - y0) * idy;
    float tx0 = fminf(ta, tb), tx1 = fmaxf(ta, tb);
    float ty0 = fminf(tc, td), ty1 = fmaxf(tc, td);
    float t0 = fmaxf(fmaxf(tx0, ty0), 0.f);   // -> v_max3
    float t1 = fminf(fminf(tx1, ty1), 1.f);   // -> v_min3
    bool valid = t1 > t0;
    float pax = fmaf(t0, dx, x0), pay = fmaf(t0, dy, y0);
    float pbx = fmaf(t1, dx, x0), pby = fmaf(t1, dy, y0);
    float c = fmaf(pax, pby, -pay * pbx);
    return valid ? c : 0.f;
}

// 4 CCW corners (cb +- u +- v in ref DX/DY order) clipped vs box
__device__ __forceinline__ float clip_quad(float cbx, float cby,
                                           float ux, float uy, float vx, float vy,
                                           float lx, float hx, float ly, float hy)
{
    float upx = ux + vx, upy = uy + vy;
    float umx = ux - vx, umy = uy - vy;
    float gx0 = cbx + upx, gy0 = cby + upy;   // (+,+)
    float gx1 = cbx - umx, gy1 = cby - umy;   // (-,+)
    float gx2 = cbx - upx, gy2 = cby - upy;   // (-,-)
    float gx3 = cbx + umx, gy3 = cby + umy;   // (+,-)
    float s = lb_edge(gx0, gy0, gx1, gy1, lx, hx, ly, hy);
    s += lb_edge(gx1, gy1, gx2, gy2, lx, hx, ly, hy);
    s += lb_edge(gx2, gy2, gx3, gy3, lx, hx, ly, hy);
    s += lb_edge(gx3, gy3, gx0, gy0, lx, hx, ly, hy);
    return s;
}

__global__ __launch_bounds__(256) void giou_partial_kernel(
    const float* __restrict__ pred, const float* __restrict__ target,
    float* __restrict__ partial, int n)
{
    __shared__ float lds[2560];          // 10 KB: 1280 pred dwords + 1280 target dwords
    const int t = threadIdx.x;
    const int base = blockIdx.x * 256;   // first box of this block
    const int i = base + t;

    float p0, p1, p2, p3, p4, q0, q1, q2, q3, q4;
    bool active = (i < n);

    if (base + 256 <= n) {
        // ---- full block: cooperative float4 staging (slice is 16B-aligned) ----
        const float4* ps = (const float4*)(pred   + (size_t)base * 5);
        const float4* ts = (const float4*)(target + (size_t)base * 5);
        ((float4*)lds)[t]          = ps[t];
        ((float4*)(lds + 1280))[t] = ts[t];
        if (t < 64) {
            ((float4*)lds)[256 + t]          = ps[256 + t];
            ((float4*)(lds + 1280))[256 + t] = ts[256 + t];
        }
        __syncthreads();
        const int o = 5 * t;
        p0 = lds[o+0]; p1 = lds[o+1]; p2 = lds[o+2]; p3 = lds[o+3]; p4 = lds[o+4];
        q0 = lds[1280+o+0]; q1 = lds[1280+o+1]; q2 = lds[1280+o+2]; q3 = lds[1280+o+3]; q4 = lds[1280+o+4];
    } else {
        // ---- tail block: guarded scalar loads ----
        int j = active ? i : 0;
        p0 = pred[5*j+0]; p1 = pred[5*j+1]; p2 = pred[5*j+2]; p3 = pred[5*j+3]; p4 = pred[5*j+4];
        q0 = target[5*j+0]; q1 = target[5*j+1]; q2 = target[5*j+2]; q3 = target[5*j+3]; q4 = target[5*j+4];
    }

    float loss = 0.0f;
    if (active) {
        // A center relative to midpoint of centers; B center is exactly -oa
        const float oaX = 0.5f*(p0 - q0), oaY = 0.5f*(p1 - q1);
        const float hw1 = 0.5f*p2, hh1 = 0.5f*p3, hw2 = 0.5f*q2, hh2 = 0.5f*q3;

        const float cs1 = __cosf(p4), sn1 = __sinf(p4);
        const float cs2 = __cosf(q4), sn2 = __sinf(q4);
        const float cD = cs1*cs2 + sn1*sn2;   // cos(a2-a1)
        const float sD = sn2*cs1 - cs2*sn1;   // sin(a2-a1)

        // ---- frame A (rotate world by -a1, origin = midpoint) ----
        const float caX =  oaX*cs1 + oaY*sn1;
        const float caY = -oaX*sn1 + oaY*cs1;
        float twoA = clip_quad(-caX, -caY,
                               cD*hw2,  sD*hw2, -sD*hh2, cD*hh2,
                               caX - hw1, caX + hw1, caY - hh1, caY + hh1);

        // ---- frame B (rotate world by -a2) ----
        const float caX2 =  oaX*cs2 + oaY*sn2;
        const float caY2 = -oaX*sn2 + oaY*cs2;
        twoA += clip_quad(caX2, caY2,
                          cD*hw1, -sD*hw1, sD*hh1, cD*hh1,
                          -caX2 - hw2, -caX2 + hw2, -caY2 - hh2, -caY2 + hh2);

        float inter_area = 0.5f * fabsf(twoA);

        // ---- union / iou ----
        float unionv = p2*p3 + q2*q3 - inter_area;
        float iou = fmaxf(inter_area * frcp(unionv), 1e-6f);

        // ---- smallest enclosing rect: 2 distinct directions, closed form ----
        float acd = fabsf(cD), asd = fabsf(sD);
        float eBx = hw2*acd + hh2*asd, eBy = hw2*asd + hh2*acd;
        float w1 = fmaxf(caX + hw1, -caX + eBx) - fminf(caX - hw1, -caX - eBx);
        float h1 = fmaxf(caY + hh1, -caY + eBy) - fminf(caY - hh1, -caY - eBy);
        float a1 = w1*h1;
        float eAx = hw1*acd + hh1*asd, eAy = hw1*asd + hh1*acd;
        float w2 = fmaxf(caX2 + eAx, -caX2 + hw2) - fminf(caX2 - eAx, -caX2 - hw2);
        float h2 = fmaxf(caY2 + eAy, -caY2 + hh2) - fminf(caY2 - eAy, -caY2 - hh2);
        float a2 = w2*h2;

        float area_c = (a2 < a1) ? a2 : a1;   // box1 dirs first in ref argmin

        float r = (area_c - unionv) * frcp(area_c);
        float giou = iou*iou*iou - r*r*r;
        loss = 1.0f - giou;
    }

    // ---- deterministic block reduction ----
    #pragma unroll
    for (int off = 32; off; off >>= 1) loss += __shfl_down(loss, off, 64);
    __shared__ float smem[4];
    int lane = threadIdx.x & 63, wid = threadIdx.x >> 6;
    __syncthreads();                      // protect lds reuse boundary & smem
    if (lane == 0) smem[wid] = loss;
    __syncthreads();
    if (threadIdx.x == 0) {
        partial[blockIdx.x] = smem[0] + smem[1] + smem[2] + smem[3];
    }
}

__global__ __launch_bounds__(256) void reduce_final_kernel(
    const float* __restrict__ partial, int nb, float* __restrict__ out, float invn)
{
    float s = 0.f;
    for (int i = threadIdx.x; i < nb; i += 256) s += partial[i];
    #pragma unroll
    for (int off = 32; off; off >>= 1) s += __shfl_down(s, off, 64);
    __shared__ float smem[4];
    int lane = threadIdx.x & 63, wid = threadIdx.x >> 6;
    if (lane == 0) smem[wid] = s;
    __syncthreads();
    if (threadIdx.x == 0) {
        out[0] = (smem[0] + smem[1] + smem[2] + smem[3]) * invn;
    }
}

extern "C" void kernel_launch(void* const* d_in, const int* in_sizes, int n_in,
                              void* d_out, int out_size, void* d_ws, size_t ws_size,
                              hipStream_t stream) {
    const float* pred   = (const float*)d_in[0];
    const float* target = (const float*)d_in[1];
    float* out = (float*)d_out;
    float* partial = (float*)d_ws;
    int n  = in_sizes[0] / 5;
    int nb = (n + 255) / 256;
    giou_partial_kernel<<<nb, 256, 0, stream>>>(pred, target, partial, n);
    reduce_final_kernel<<<1, 256, 0, stream>>>(partial, nb, out, 1.0f/(float)n);
}